// Round 6
// baseline (450.086 us; speedup 1.0000x reference)
//
#include <hip/hip_runtime.h>
#include <hip/hip_bf16.h>

// ---------------- types & helpers ----------------
typedef __attribute__((ext_vector_type(8))) short short8;    // 8 bf16 (4 VGPR)
typedef __attribute__((ext_vector_type(4))) float f32x4;     // 16x16 MFMA C/D
typedef __attribute__((ext_vector_type(16))) float f32x16;   // 32x32 MFMA C/D
typedef __attribute__((ext_vector_type(4))) unsigned uint4v;

#define GLOB_AS __attribute__((address_space(1)))
#define LDS_AS  __attribute__((address_space(3)))

__device__ __forceinline__ void async16(void* lds, const void* g) {
  __builtin_amdgcn_global_load_lds((const GLOB_AS unsigned int*)g,
                                   (LDS_AS unsigned int*)lds, 16, 0, 0);
}

__device__ __forceinline__ unsigned short f2bf(float f) {
  unsigned u = __float_as_uint(f);
  unsigned r = u + 0x7FFFu + ((u >> 16) & 1u);   // RNE
  return (unsigned short)(r >> 16);
}

__device__ __forceinline__ float bf2f(unsigned short u) {
  unsigned x = ((unsigned)u) << 16;
  return __uint_as_float(x);
}

__device__ __forceinline__ unsigned pk2(float lo, float hi) {
  __hip_bfloat162 h = __float22bfloat162_rn(float2{lo, hi});
  return *reinterpret_cast<unsigned*>(&h);
}

// exchange halves: a' = [a.lo | b.lo], b' = [a.hi | b.hi]
__device__ __forceinline__ void lane32_swap(unsigned& a, unsigned& b, int lane) {
#if __has_builtin(__builtin_amdgcn_permlane32_swap)
  auto r = __builtin_amdgcn_permlane32_swap(a, b, false, false);
  a = r[0]; b = r[1];
#else
  unsigned tb = __shfl_xor(b, 32);
  unsigned ta = __shfl_xor(a, 32);
  unsigned na = (lane < 32) ? a : tb;
  unsigned nb = (lane < 32) ? ta : b;
  a = na; b = nb;
#endif
}

// dims
#define BATCH 4
#define SEQ   2048
#define DMODEL 1024
#define NHEAD 4
#define HD    256

// Q pre-scale: 1/sqrt(256) * log2(e)  (softmax done in exp2 domain)
#define QSCALE 0.090169944f
#define DEFER_THR 11.5f

// ---------------- cast x -> bf16 ----------------
__global__ __launch_bounds__(256) void cast_bf16_kernel(
    const float* __restrict__ in, unsigned short* __restrict__ out) {
  int i = blockIdx.x * 256 + threadIdx.x;   // handles 4 elements
  float4 v = ((const float4*)in)[i];
  uint2 o;
  o.x = (unsigned)f2bf(v.x) | ((unsigned)f2bf(v.y) << 16);
  o.y = (unsigned)f2bf(v.z) | ((unsigned)f2bf(v.w) << 16);
  ((uint2*)out)[i] = o;
}

// ---------------- transpose + cast weights: out[c][r] = bf16(in[r][c]) ----------------
__global__ __launch_bounds__(256) void transpose_cast_kernel(
    const float* __restrict__ in, unsigned short* __restrict__ out, int R, int C) {
  __shared__ float tile[32][33];
  int c0 = blockIdx.x * 32, r0 = blockIdx.y * 32;
  int tx = threadIdx.x, ty = threadIdx.y;  // (32, 8)
#pragma unroll
  for (int i = 0; i < 4; ++i)
    tile[ty + 8 * i][tx] = in[(size_t)(r0 + ty + 8 * i) * C + c0 + tx];
  __syncthreads();
#pragma unroll
  for (int i = 0; i < 4; ++i)
    out[(size_t)(c0 + ty + 8 * i) * R + r0 + tx] = f2bf(tile[tx][ty + 8 * i]);
}

// ---------------- QKV GEMM: C[8192,3072] = xb * wqkvT^T + b ----------------
// Q written pre-scaled by QSCALE; V written in tiled layout [bh][kp>>4][d][kp&15].
__global__ __launch_bounds__(256) void gemm_qkv_kernel(
    const unsigned short* __restrict__ A,    // xb   [8192][1024]
    const unsigned short* __restrict__ Bt,   // wqkvT[3072][1024]
    const float* __restrict__ bias,          // [3072]
    unsigned short* __restrict__ qb,         // [16][2048][256]  (scaled)
    unsigned short* __restrict__ kb,         // [16][2048][256]
    unsigned short* __restrict__ vt) {       // [16][128][256][16] tiled V^T
  __shared__ __align__(16) unsigned short sA[128 * 32];
  __shared__ __align__(16) unsigned short sB[128 * 32];
  const int t = threadIdx.x;
  const int l = t & 63, w = t >> 6;
  const int g = l >> 4, lr = l & 15;
  const int wr = w >> 1, wc = w & 1;
  const int row0 = blockIdx.y * 128;
  const int col0 = blockIdx.x * 128;

  f32x4 acc[4][4] = {};
  for (int kt = 0; kt < 1024; kt += 32) {
    __syncthreads();
#pragma unroll
    for (int i = 0; i < 2; ++i) {
      int e = i * 256 + t;
      async16(&sA[e * 8], A + (size_t)(row0 + (e >> 2)) * 1024 + kt + (e & 3) * 8);
      async16(&sB[e * 8], Bt + (size_t)(col0 + (e >> 2)) * 1024 + kt + (e & 3) * 8);
    }
    __syncthreads();
    short8 af[4], bf[4];
#pragma unroll
    for (int m = 0; m < 4; ++m)
      af[m] = *(const short8*)&sA[(wr * 64 + m * 16 + lr) * 32 + g * 8];
#pragma unroll
    for (int n = 0; n < 4; ++n)
      bf[n] = *(const short8*)&sB[(wc * 64 + n * 16 + lr) * 32 + g * 8];
#pragma unroll
    for (int m = 0; m < 4; ++m)
#pragma unroll
      for (int n = 0; n < 4; ++n)
        acc[m][n] = __builtin_amdgcn_mfma_f32_16x16x32_bf16(af[m], bf[n], acc[m][n], 0, 0, 0);
  }

  // epilogue: C layout col=lane&15, row=(lane>>4)*4+reg
#pragma unroll
  for (int m = 0; m < 4; ++m) {
    int rowb = row0 + wr * 64 + m * 16 + g * 4;  // + rr
    int b = rowb >> 11;
    int nb = rowb & 2047;
#pragma unroll
    for (int nn = 0; nn < 4; ++nn) {
      int col = col0 + wc * 64 + nn * 16 + lr;
      float bv = bias[col];
      int sec = col >> 10, c1 = col & 1023;
      int h = c1 >> 8, d = c1 & 255;
      if (sec == 2) {  // V -> tiled [bh][kp>>4][d][kp&15], pack 4 consecutive kp
        unsigned short p0 = f2bf(acc[m][nn][0] + bv);
        unsigned short p1 = f2bf(acc[m][nn][1] + bv);
        unsigned short p2 = f2bf(acc[m][nn][2] + bv);
        unsigned short p3 = f2bf(acc[m][nn][3] + bv);
        uint2 pk;
        pk.x = (unsigned)p0 | ((unsigned)p1 << 16);
        pk.y = (unsigned)p2 | ((unsigned)p3 << 16);
        size_t idx = (((size_t)((b * NHEAD + h) * 128 + (nb >> 4))) * 256 + d) * 16 + (nb & 15);
        *(uint2*)&vt[idx] = pk;
      } else {
        unsigned short* dst = (sec == 0) ? qb : kb;
        float sc = (sec == 0) ? QSCALE : 1.0f;
#pragma unroll
        for (int rr = 0; rr < 4; ++rr) {
          size_t idx = ((size_t)((b * NHEAD + h) * SEQ + nb + rr)) * HD + d;
          dst[idx] = f2bf((acc[m][nn][rr] + bv) * sc);
        }
      }
    }
  }
}

// ---------------- attention (KV-split 2) ----------------
// 4 waves/block, 32 q rows per wave, mfma_32x32x16, swapped orientation.
// Each block processes HALF the key range (1024 kp = 32 chunks), writes
// normalized partial O (bf16) + per-q (m, l) stats; combine_kernel merges.
// Grid 512 -> 2 blocks/CU -> 2 waves/SIMD for latency hiding.
__global__ __launch_bounds__(256, 2) void attn_kernel(
    const unsigned short* __restrict__ qb,
    const unsigned short* __restrict__ kb,
    const unsigned short* __restrict__ vt,   // tiled [16][128][256][16]
    unsigned short* __restrict__ Oh,         // [2][8192][1024] bf16 partials
    float2* __restrict__ st) {               // [2][16][2048] (m, l)
  __shared__ __align__(16) unsigned short sK[2][32 * 256];   // 16 KB per buffer
  const int t = threadIdx.x, l = t & 63, w = t >> 6;
  const int row = l & 31, hi = l >> 5;
  const int swz = (row & 7) << 4;
  // XCD-aware decode: bid%8 == XCD; XCD x owns heads {2x, 2x+1};
  // both KV-halves of a head land on the same XCD.
  const int bid = blockIdx.x;
  const int bh = (bid & 7) * 2 + ((bid >> 3) & 1);
  const int qblk = (bid >> 4) & 15;          // 0..15, 128 q per block
  const int kvhalf = bid >> 8;               // 0..1
  const int b = bh >> 2, h = bh & 3;
  const int q = qblk * 128 + w * 32 + row;
  const unsigned short* Qp = qb + (size_t)bh * SEQ * HD;
  const char* Kg = (const char*)(kb + (size_t)bh * SEQ * HD);
  const unsigned short* Vb = vt + (size_t)bh * (128 * 256 * 16);

  // Q B-frags: lane col=q=row, k = dc*16 + hi*8 + j
  short8 qf[16];
#pragma unroll
  for (int dc = 0; dc < 16; ++dc)
    qf[dc] = *(const short8*)&Qp[(size_t)q * HD + dc * 16 + hi * 8];

  auto stage = [&](int buf, int kp0) {
#pragma unroll
    for (int i = 0; i < 4; ++i) {
      int s = i * 256 + t;                   // 16B slot index, 0..1023
      int r = s >> 5;                        // 0..31
      int colb = (s & 31) * 16;
      int src = (kp0 + r) * 512 + (colb ^ ((r & 7) << 4));
      async16((char*)sK[buf] + s * 16, Kg + src);
    }
  };

  const int kpbase = kvhalf * 1024;
  stage(0, kpbase);
  __syncthreads();

  f32x16 O[8] = {};
  float mrun = -__builtin_inff();
  float lsum = 0.f;

  for (int it = 0; it < 32; ++it) {
    const int kp0 = kpbase + it * 32;
    const int cur = it & 1;
    if (it < 31) stage(cur ^ 1, kp0 + 32);   // async prefetch next K chunk

    // V A-frags for this chunk, direct from L2 (consumed after softmax)
    short8 vfr[8][2];
#pragma unroll
    for (int db = 0; db < 8; ++db)
#pragma unroll
      for (int kh = 0; kh < 2; ++kh)
        vfr[db][kh] = *(const short8*)&Vb[(((size_t)((kp0 >> 4) + kh)) * 256 +
                                           db * 32 + row) * 16 + hi * 8];

    // QK^T: S^T[32 kp][32 q], two independent 8-deep chains
    f32x16 Sa = {}, Sb = {};
    const char* sKc = (const char*)sK[cur];
#pragma unroll
    for (int dc = 0; dc < 16; dc += 2) {
      short8 kf0 = *(const short8*)(sKc + row * 512 + ((dc * 32 + hi * 16) ^ swz));
      short8 kf1 = *(const short8*)(sKc + row * 512 + (((dc + 1) * 32 + hi * 16) ^ swz));
      Sa = __builtin_amdgcn_mfma_f32_32x32x16_bf16(kf0, qf[dc], Sa, 0, 0, 0);
      Sb = __builtin_amdgcn_mfma_f32_32x32x16_bf16(kf1, qf[dc + 1], Sb, 0, 0, 0);
    }

    // in-register softmax (exp2 domain; Q pre-scaled by 1/16*log2e)
    float p[16];
#pragma unroll
    for (int i = 0; i < 16; ++i) p[i] = Sa[i] + Sb[i];
    float m0 = fmaxf(fmaxf(fmaxf(p[0], p[1]), fmaxf(p[2], p[3])),
                     fmaxf(fmaxf(p[4], p[5]), fmaxf(p[6], p[7])));
    float m1 = fmaxf(fmaxf(fmaxf(p[8], p[9]), fmaxf(p[10], p[11])),
                     fmaxf(fmaxf(p[12], p[13]), fmaxf(p[14], p[15])));
    float cmax = fmaxf(m0, m1);
    cmax = fmaxf(cmax, __shfl_xor(cmax, 32));

    if (!__all(cmax <= mrun + DEFER_THR)) {
      float mnew = fmaxf(mrun, cmax);
      float alpha = exp2f(mrun - mnew);
      lsum *= alpha;
#pragma unroll
      for (int db = 0; db < 8; ++db) O[db] *= alpha;
      mrun = mnew;
    }

    float e[16];
#pragma unroll
    for (int i = 0; i < 16; ++i) e[i] = exp2f(p[i] - mrun);
    float s0 = (e[0] + e[1]) + (e[2] + e[3]);
    float s1 = (e[4] + e[5]) + (e[6] + e[7]);
    float s2 = (e[8] + e[9]) + (e[10] + e[11]);
    float s3 = (e[12] + e[13]) + (e[14] + e[15]);
    float ps = (s0 + s1) + (s2 + s3);
    ps += __shfl_xor(ps, 32);
    lsum += ps;

    // P B-frags in-register.
    // lane's S reg r holds kp = (r&3) + 8*(r>>2) + 4*hi.
    unsigned a0 = pk2(e[0], e[1]),   a1 = pk2(e[2], e[3]);
    unsigned b0 = pk2(e[4], e[5]),   b1 = pk2(e[6], e[7]);
    unsigned c0 = pk2(e[8], e[9]),   c1 = pk2(e[10], e[11]);
    unsigned d0 = pk2(e[12], e[13]), d1 = pk2(e[14], e[15]);
    lane32_swap(a0, b0, l);
    lane32_swap(a1, b1, l);
    lane32_swap(c0, d0, l);
    lane32_swap(c1, d1, l);
    uint4v u1; u1.x = a0; u1.y = a1; u1.z = b0; u1.w = b1;
    uint4v u2; u2.x = c0; u2.y = c1; u2.z = d0; u2.w = d1;
    short8 pf1 = __builtin_bit_cast(short8, u1);   // kp 0..15
    short8 pf2 = __builtin_bit_cast(short8, u2);   // kp 16..31

    // PV: O^T[d][q] accumulate
#pragma unroll
    for (int db = 0; db < 8; ++db) {
      O[db] = __builtin_amdgcn_mfma_f32_32x32x16_bf16(vfr[db][0], pf1, O[db], 0, 0, 0);
      O[db] = __builtin_amdgcn_mfma_f32_32x32x16_bf16(vfr[db][1], pf2, O[db], 0, 0, 0);
    }

    __syncthreads();   // drains stage loads + swaps buffers
  }

  float inv = 1.0f / lsum;
  unsigned short* aop = Oh + (size_t)kvhalf * (8192ull * 1024);
  size_t obase = ((size_t)(b * SEQ + q)) * DMODEL + h * HD;
#pragma unroll
  for (int db = 0; db < 8; ++db)
#pragma unroll
    for (int rg = 0; rg < 4; ++rg) {
      int dd = db * 32 + rg * 8 + hi * 4;
      uint2 pk;
      pk.x = pk2(O[db][rg * 4 + 0] * inv, O[db][rg * 4 + 1] * inv);
      pk.y = pk2(O[db][rg * 4 + 2] * inv, O[db][rg * 4 + 3] * inv);
      *(uint2*)&aop[obase + dd] = pk;
    }
  if (hi == 0)
    st[((size_t)kvhalf * 16 + bh) * 2048 + q] = make_float2(mrun, lsum);
}

// ---------------- combine KV-split halves ----------------
__global__ __launch_bounds__(256) void combine_kernel(
    const unsigned short* __restrict__ Oh,   // [2][8192][1024]
    const float2* __restrict__ st,           // [2][16][2048]
    unsigned short* __restrict__ ao) {       // [8192][1024]
  int rowg = blockIdx.x, t = threadIdx.x;
  int b = rowg >> 11, q = rowg & 2047;
  int col = t * 4;
  int bh = b * 4 + (col >> 8);
  float2 s0 = st[(size_t)bh * 2048 + q];
  float2 s1 = st[(16ull * 2048) + (size_t)bh * 2048 + q];
  float M = fmaxf(s0.x, s1.x);
  float w0 = s0.y * exp2f(s0.x - M);
  float w1 = s1.y * exp2f(s1.x - M);
  float inv = 1.0f / (w0 + w1);
  w0 *= inv; w1 *= inv;
  size_t base = (size_t)rowg * 1024 + col;
  uint2 ua = *(const uint2*)&Oh[base];
  uint2 ub = *(const uint2*)&Oh[8192ull * 1024 + base];
  unsigned short oa[4] = {(unsigned short)(ua.x & 0xFFFF), (unsigned short)(ua.x >> 16),
                          (unsigned short)(ua.y & 0xFFFF), (unsigned short)(ua.y >> 16)};
  unsigned short ob[4] = {(unsigned short)(ub.x & 0xFFFF), (unsigned short)(ub.x >> 16),
                          (unsigned short)(ub.y & 0xFFFF), (unsigned short)(ub.y >> 16)};
  float r[4];
#pragma unroll
  for (int j = 0; j < 4; ++j) r[j] = w0 * bf2f(oa[j]) + w1 * bf2f(ob[j]);
  uint2 pk;
  pk.x = pk2(r[0], r[1]);
  pk.y = pk2(r[2], r[3]);
  *(uint2*)&ao[base] = pk;
}

// ---------------- out projection + bias + residual -> y (fp32) ----------------
__global__ __launch_bounds__(256) void gemm_out_kernel(
    const unsigned short* __restrict__ A,    // attn_out [8192][1024]
    const unsigned short* __restrict__ Bt,   // woutT    [1024][1024]
    const float* __restrict__ bias,          // [1024]
    const float* __restrict__ x,             // [8192][1024] fp32
    float* __restrict__ y) {                 // [8192][1024] fp32
  __shared__ __align__(16) unsigned short sA[128 * 32];
  __shared__ __align__(16) unsigned short sB[128 * 32];
  const int t = threadIdx.x;
  const int l = t & 63, w = t >> 6;
  const int g = l >> 4, lr = l & 15;
  const int wr = w >> 1, wc = w & 1;
  const int row0 = blockIdx.y * 128;
  const int col0 = blockIdx.x * 128;

  f32x4 acc[4][4] = {};
  for (int kt = 0; kt < 1024; kt += 32) {
    __syncthreads();
#pragma unroll
    for (int i = 0; i < 2; ++i) {
      int e = i * 256 + t;
      async16(&sA[e * 8], A + (size_t)(row0 + (e >> 2)) * 1024 + kt + (e & 3) * 8);
      async16(&sB[e * 8], Bt + (size_t)(col0 + (e >> 2)) * 1024 + kt + (e & 3) * 8);
    }
    __syncthreads();
    short8 af[4], bf[4];
#pragma unroll
    for (int m = 0; m < 4; ++m)
      af[m] = *(const short8*)&sA[(wr * 64 + m * 16 + lr) * 32 + g * 8];
#pragma unroll
    for (int n = 0; n < 4; ++n)
      bf[n] = *(const short8*)&sB[(wc * 64 + n * 16 + lr) * 32 + g * 8];
#pragma unroll
    for (int m = 0; m < 4; ++m)
#pragma unroll
      for (int n = 0; n < 4; ++n)
        acc[m][n] = __builtin_amdgcn_mfma_f32_16x16x32_bf16(af[m], bf[n], acc[m][n], 0, 0, 0);
  }

#pragma unroll
  for (int m = 0; m < 4; ++m) {
    int rowb = row0 + wr * 64 + m * 16 + g * 4;
#pragma unroll
    for (int nn = 0; nn < 4; ++nn) {
      int col = col0 + wc * 64 + nn * 16 + lr;
      float bv = bias[col];
#pragma unroll
      for (int rr = 0; rr < 4; ++rr) {
        size_t idx = (size_t)(rowb + rr) * 1024 + col;
        y[idx] = acc[m][nn][rr] + bv + x[idx];
      }
    }
  }
}

// ---------------- LayerNorm over last dim (1024) ----------------
__global__ __launch_bounds__(256) void ln_kernel(
    const float* __restrict__ y, const float* __restrict__ gamma,
    const float* __restrict__ beta, float* __restrict__ out) {
  int row = blockIdx.x, t = threadIdx.x;
  float4 v = ((const float4*)(y + (size_t)row * 1024))[t];
  float s = v.x + v.y + v.z + v.w;
  float qs = v.x * v.x + v.y * v.y + v.z * v.z + v.w * v.w;
#pragma unroll
  for (int off = 1; off < 64; off <<= 1) {
    s += __shfl_xor(s, off);
    qs += __shfl_xor(qs, off);
  }
  __shared__ float ss[4], qq[4];
  if ((t & 63) == 0) { ss[t >> 6] = s; qq[t >> 6] = qs; }
  __syncthreads();
  s = ss[0] + ss[1] + ss[2] + ss[3];
  qs = qq[0] + qq[1] + qq[2] + qq[3];
  float mean = s * (1.0f / 1024.0f);
  float var = qs * (1.0f / 1024.0f) - mean * mean;
  float rstd = rsqrtf(var + 1e-5f);
  float4 gm = ((const float4*)gamma)[t];
  float4 bt = ((const float4*)beta)[t];
  float4 o;
  o.x = (v.x - mean) * rstd * gm.x + bt.x;
  o.y = (v.y - mean) * rstd * gm.y + bt.y;
  o.z = (v.z - mean) * rstd * gm.z + bt.z;
  o.w = (v.w - mean) * rstd * gm.w + bt.w;
  ((float4*)(out + (size_t)row * 1024))[t] = o;
}

// ---------------- launch ----------------
extern "C" void kernel_launch(void* const* d_in, const int* in_sizes, int n_in,
                              void* d_out, int out_size, void* d_ws, size_t ws_size,
                              hipStream_t stream) {
  const float* x      = (const float*)d_in[0];
  const float* w_qkv  = (const float*)d_in[1];
  const float* b_qkv  = (const float*)d_in[2];
  const float* w_out  = (const float*)d_in[3];
  const float* b_out  = (const float*)d_in[4];
  const float* gamma  = (const float*)d_in[5];
  const float* beta   = (const float*)d_in[6];
  float* out = (float*)d_out;

  char* ws = (char*)d_ws;
  unsigned short* xb    = (unsigned short*)(ws);                 // 16 MB
  unsigned short* wqkvT = (unsigned short*)(ws + (16u << 20));   //  6 MB
  unsigned short* woutT = (unsigned short*)(ws + (22u << 20));   //  2 MB
  unsigned short* qb    = (unsigned short*)(ws + (24u << 20));   // 16 MB
  unsigned short* kb    = (unsigned short*)(ws + (40u << 20));   // 16 MB
  unsigned short* vt    = (unsigned short*)(ws + (56u << 20));   // 16 MB
  unsigned short* ao    = (unsigned short*)(ws + (72u << 20));   // 16 MB
  unsigned short* Oh    = (unsigned short*)(ws + (88u << 20));   // 32 MB (dead after combine)
  float* y              = (float*)(ws + (88u << 20));            // 32 MB (after combine)
  float2* st            = (float2*)(ws + (16u << 20));           // 512 KB (overlays dead wqkvT)

  cast_bf16_kernel<<<(BATCH * SEQ * DMODEL) / (256 * 4), 256, 0, stream>>>(x, xb);
  transpose_cast_kernel<<<dim3(96, 32), dim3(32, 8), 0, stream>>>(w_qkv, wqkvT, 1024, 3072);
  transpose_cast_kernel<<<dim3(32, 32), dim3(32, 8), 0, stream>>>(w_out, woutT, 1024, 1024);
  gemm_qkv_kernel<<<dim3(24, 64), 256, 0, stream>>>(xb, wqkvT, b_qkv, qb, kb, vt);
  attn_kernel<<<512, 256, 0, stream>>>(qb, kb, vt, Oh, st);
  combine_kernel<<<BATCH * SEQ, 256, 0, stream>>>(Oh, st, ao);
  gemm_out_kernel<<<dim3(8, 64), 256, 0, stream>>>(ao, woutT, b_out, x, y);
  ln_kernel<<<BATCH * SEQ, 256, 0, stream>>>(y, gamma, beta, out);
}

// Round 7
// 244.730 us; speedup vs baseline: 1.8391x; 1.8391x over previous
//
#include <hip/hip_runtime.h>
#include <hip/hip_bf16.h>

// ---------------- types & helpers ----------------
typedef __attribute__((ext_vector_type(8))) short short8;    // 8 bf16 (4 VGPR)
typedef __attribute__((ext_vector_type(4))) float f32x4;     // 16x16 MFMA C/D
typedef __attribute__((ext_vector_type(16))) float f32x16;   // 32x32 MFMA C/D
typedef __attribute__((ext_vector_type(4))) unsigned uint4v;

#define GLOB_AS __attribute__((address_space(1)))
#define LDS_AS  __attribute__((address_space(3)))

__device__ __forceinline__ void async16(void* lds, const void* g) {
  __builtin_amdgcn_global_load_lds((const GLOB_AS unsigned int*)g,
                                   (LDS_AS unsigned int*)lds, 16, 0, 0);
}

__device__ __forceinline__ unsigned short f2bf(float f) {
  unsigned u = __float_as_uint(f);
  unsigned r = u + 0x7FFFu + ((u >> 16) & 1u);   // RNE
  return (unsigned short)(r >> 16);
}

__device__ __forceinline__ float bf2f(unsigned short u) {
  unsigned x = ((unsigned)u) << 16;
  return __uint_as_float(x);
}

__device__ __forceinline__ unsigned pk2(float lo, float hi) {
  __hip_bfloat162 h = __float22bfloat162_rn(float2{lo, hi});
  return *reinterpret_cast<unsigned*>(&h);
}

// exchange halves: a' = [a.lo | b.lo], b' = [a.hi | b.hi]
__device__ __forceinline__ void lane32_swap(unsigned& a, unsigned& b, int lane) {
#if __has_builtin(__builtin_amdgcn_permlane32_swap)
  auto r = __builtin_amdgcn_permlane32_swap(a, b, false, false);
  a = r[0]; b = r[1];
#else
  unsigned tb = __shfl_xor(b, 32);
  unsigned ta = __shfl_xor(a, 32);
  unsigned na = (lane < 32) ? a : tb;
  unsigned nb = (lane < 32) ? ta : b;
  a = na; b = nb;
#endif
}

// dims
#define BATCH 4
#define SEQ   2048
#define DMODEL 1024
#define NHEAD 4
#define HD    256

// Q pre-scale: 1/sqrt(256) * log2(e)  (softmax done in exp2 domain)
#define QSCALE 0.090169944f
#define DEFER_THR 11.5f

// ---------------- cast x -> bf16 ----------------
__global__ __launch_bounds__(256) void cast_bf16_kernel(
    const float* __restrict__ in, unsigned short* __restrict__ out) {
  int i = blockIdx.x * 256 + threadIdx.x;   // handles 4 elements
  float4 v = ((const float4*)in)[i];
  uint2 o;
  o.x = (unsigned)f2bf(v.x) | ((unsigned)f2bf(v.y) << 16);
  o.y = (unsigned)f2bf(v.z) | ((unsigned)f2bf(v.w) << 16);
  ((uint2*)out)[i] = o;
}

// ---------------- transpose + cast weights: out[c][r] = bf16(in[r][c]) ----------------
__global__ __launch_bounds__(256) void transpose_cast_kernel(
    const float* __restrict__ in, unsigned short* __restrict__ out, int R, int C) {
  __shared__ float tile[32][33];
  int c0 = blockIdx.x * 32, r0 = blockIdx.y * 32;
  int tx = threadIdx.x, ty = threadIdx.y;  // (32, 8)
#pragma unroll
  for (int i = 0; i < 4; ++i)
    tile[ty + 8 * i][tx] = in[(size_t)(r0 + ty + 8 * i) * C + c0 + tx];
  __syncthreads();
#pragma unroll
  for (int i = 0; i < 4; ++i)
    out[(size_t)(c0 + ty + 8 * i) * R + r0 + tx] = f2bf(tile[tx][ty + 8 * i]);
}

// ---------------- QKV GEMM: C[8192,3072] = xb * wqkvT^T + b ----------------
// Q written pre-scaled by QSCALE; V written in tiled layout [bh][kp>>4][d][kp&15].
__global__ __launch_bounds__(256) void gemm_qkv_kernel(
    const unsigned short* __restrict__ A,    // xb   [8192][1024]
    const unsigned short* __restrict__ Bt,   // wqkvT[3072][1024]
    const float* __restrict__ bias,          // [3072]
    unsigned short* __restrict__ qb,         // [16][2048][256]  (scaled)
    unsigned short* __restrict__ kb,         // [16][2048][256]
    unsigned short* __restrict__ vt) {       // [16][128][256][16] tiled V^T
  __shared__ __align__(16) unsigned short sA[128 * 32];
  __shared__ __align__(16) unsigned short sB[128 * 32];
  const int t = threadIdx.x;
  const int l = t & 63, w = t >> 6;
  const int g = l >> 4, lr = l & 15;
  const int wr = w >> 1, wc = w & 1;
  const int row0 = blockIdx.y * 128;
  const int col0 = blockIdx.x * 128;

  f32x4 acc[4][4] = {};
  for (int kt = 0; kt < 1024; kt += 32) {
    __syncthreads();
#pragma unroll
    for (int i = 0; i < 2; ++i) {
      int e = i * 256 + t;
      async16(&sA[e * 8], A + (size_t)(row0 + (e >> 2)) * 1024 + kt + (e & 3) * 8);
      async16(&sB[e * 8], Bt + (size_t)(col0 + (e >> 2)) * 1024 + kt + (e & 3) * 8);
    }
    __syncthreads();
    short8 af[4], bf[4];
#pragma unroll
    for (int m = 0; m < 4; ++m)
      af[m] = *(const short8*)&sA[(wr * 64 + m * 16 + lr) * 32 + g * 8];
#pragma unroll
    for (int n = 0; n < 4; ++n)
      bf[n] = *(const short8*)&sB[(wc * 64 + n * 16 + lr) * 32 + g * 8];
#pragma unroll
    for (int m = 0; m < 4; ++m)
#pragma unroll
      for (int n = 0; n < 4; ++n)
        acc[m][n] = __builtin_amdgcn_mfma_f32_16x16x32_bf16(af[m], bf[n], acc[m][n], 0, 0, 0);
  }

  // epilogue: C layout col=lane&15, row=(lane>>4)*4+reg
#pragma unroll
  for (int m = 0; m < 4; ++m) {
    int rowb = row0 + wr * 64 + m * 16 + g * 4;  // + rr
    int b = rowb >> 11;
    int nb = rowb & 2047;
#pragma unroll
    for (int nn = 0; nn < 4; ++nn) {
      int col = col0 + wc * 64 + nn * 16 + lr;
      float bv = bias[col];
      int sec = col >> 10, c1 = col & 1023;
      int h = c1 >> 8, d = c1 & 255;
      if (sec == 2) {  // V -> tiled [bh][kp>>4][d][kp&15], pack 4 consecutive kp
        unsigned short p0 = f2bf(acc[m][nn][0] + bv);
        unsigned short p1 = f2bf(acc[m][nn][1] + bv);
        unsigned short p2 = f2bf(acc[m][nn][2] + bv);
        unsigned short p3 = f2bf(acc[m][nn][3] + bv);
        uint2 pk;
        pk.x = (unsigned)p0 | ((unsigned)p1 << 16);
        pk.y = (unsigned)p2 | ((unsigned)p3 << 16);
        size_t idx = (((size_t)((b * NHEAD + h) * 128 + (nb >> 4))) * 256 + d) * 16 + (nb & 15);
        *(uint2*)&vt[idx] = pk;
      } else {
        unsigned short* dst = (sec == 0) ? qb : kb;
        float sc = (sec == 0) ? QSCALE : 1.0f;
#pragma unroll
        for (int rr = 0; rr < 4; ++rr) {
          size_t idx = ((size_t)((b * NHEAD + h) * SEQ + nb + rr)) * HD + d;
          dst[idx] = f2bf((acc[m][nn][rr] + bv) * sc);
        }
      }
    }
  }
}

// ---------------- attention (KV-split 2, INTERLEAVED chunks) ----------------
// 4 waves/block, 32 q rows per wave, mfma_32x32x16, swapped orientation.
// kvhalf=0 processes even 32-row chunks, kvhalf=1 odd chunks -> all 32 blocks
// of a head walk the SAME K/V window in lockstep (L2-resident stream).
// K chunk [32][256] XOR-swizzled and V chunk [2][256][16] linear, both
// double-buffered in LDS via global_load_lds (64 KB total, 2 blocks/CU).
__global__ __launch_bounds__(256, 2) void attn_kernel(
    const unsigned short* __restrict__ qb,
    const unsigned short* __restrict__ kb,
    const unsigned short* __restrict__ vt,   // tiled [16][128][256][16]
    unsigned short* __restrict__ Oh,         // [2][8192][1024] bf16 partials
    float2* __restrict__ st) {               // [2][16][2048] (m, l)
  __shared__ __align__(16) unsigned short sK[2][32 * 256];   // 16 KB per buffer
  __shared__ __align__(16) unsigned short sV[2][2 * 256 * 16]; // 16 KB per buffer
  const int t = threadIdx.x, l = t & 63, w = t >> 6;
  const int row = l & 31, hi = l >> 5;
  const int swz = (row & 7) << 4;
  // XCD-aware decode: bid%8 == XCD; XCD x owns heads {2x, 2x+1};
  // both KV-halves of a head land on the same XCD.
  const int bid = blockIdx.x;
  const int bh = (bid & 7) * 2 + ((bid >> 3) & 1);
  const int qblk = (bid >> 4) & 15;          // 0..15, 128 q per block
  const int kvhalf = bid >> 8;               // 0..1 (interleaved chunk parity)
  const int b = bh >> 2, h = bh & 3;
  const int q = qblk * 128 + w * 32 + row;
  const unsigned short* Qp = qb + (size_t)bh * SEQ * HD;
  const char* Kg = (const char*)(kb + (size_t)bh * SEQ * HD);
  const char* Vg = (const char*)(vt + (size_t)bh * (128 * 256 * 16));

  // Q B-frags: lane col=q=row, k = dc*16 + hi*8 + j
  short8 qf[16];
#pragma unroll
  for (int dc = 0; dc < 16; ++dc)
    qf[dc] = *(const short8*)&Qp[(size_t)q * HD + dc * 16 + hi * 8];

  // stage K chunk [kp0..kp0+32)x[256] (inverse-swizzled src, linear dest)
  // and V chunk [2][256][16] (linear src+dest) into LDS buffers.
  auto stage = [&](int buf, int kp0) {
#pragma unroll
    for (int i = 0; i < 4; ++i) {
      int s = i * 256 + t;                   // 16B granule, 0..1023
      int r = s >> 5;                        // 0..31
      int colb = (s & 31) * 16;
      int src = (kp0 + r) * 512 + (colb ^ ((r & 7) << 4));
      async16((char*)sK[buf] + s * 16, Kg + src);
    }
    const int c0 = kp0 >> 4;                 // V chunk index (2 chunks of 16 kp)
#pragma unroll
    for (int i = 0; i < 4; ++i) {
      int s = i * 256 + t;                   // 16B granule, 0..1023
      int kh = s >> 9, rem = s & 511;
      int d = rem >> 1, vhi = rem & 1;
      int src = ((c0 + kh) * 256 + d) * 32 + vhi * 16;
      async16((char*)sV[buf] + s * 16, Vg + src);
    }
  };

  // interleaved chunk schedule: chunk(it) = 2*it + kvhalf
  stage(0, kvhalf * 32);
  __syncthreads();

  f32x16 O[8] = {};
  float mrun = -__builtin_inff();
  float lsum = 0.f;

  for (int it = 0; it < 32; ++it) {
    const int kp0 = (2 * it + kvhalf) * 32;
    const int cur = it & 1;
    if (it < 31) stage(cur ^ 1, kp0 + 64);   // async prefetch next chunk

    // QK^T: S^T[32 kp][32 q], two independent 8-deep chains
    f32x16 Sa = {}, Sb = {};
    const char* sKc = (const char*)sK[cur];
    __builtin_amdgcn_s_setprio(1);
#pragma unroll
    for (int dc = 0; dc < 16; dc += 2) {
      short8 kf0 = *(const short8*)(sKc + row * 512 + ((dc * 32 + hi * 16) ^ swz));
      short8 kf1 = *(const short8*)(sKc + row * 512 + (((dc + 1) * 32 + hi * 16) ^ swz));
      Sa = __builtin_amdgcn_mfma_f32_32x32x16_bf16(kf0, qf[dc], Sa, 0, 0, 0);
      Sb = __builtin_amdgcn_mfma_f32_32x32x16_bf16(kf1, qf[dc + 1], Sb, 0, 0, 0);
    }
    __builtin_amdgcn_s_setprio(0);

    // in-register softmax (exp2 domain; Q pre-scaled by 1/16*log2e)
    float p[16];
#pragma unroll
    for (int i = 0; i < 16; ++i) p[i] = Sa[i] + Sb[i];
    float m0 = fmaxf(fmaxf(fmaxf(p[0], p[1]), fmaxf(p[2], p[3])),
                     fmaxf(fmaxf(p[4], p[5]), fmaxf(p[6], p[7])));
    float m1 = fmaxf(fmaxf(fmaxf(p[8], p[9]), fmaxf(p[10], p[11])),
                     fmaxf(fmaxf(p[12], p[13]), fmaxf(p[14], p[15])));
    float cmax = fmaxf(m0, m1);
    cmax = fmaxf(cmax, __shfl_xor(cmax, 32));

    if (!__all(cmax <= mrun + DEFER_THR)) {
      float mnew = fmaxf(mrun, cmax);
      float alpha = exp2f(mrun - mnew);
      lsum *= alpha;
#pragma unroll
      for (int db = 0; db < 8; ++db) O[db] *= alpha;
      mrun = mnew;
    }

    float e[16];
#pragma unroll
    for (int i = 0; i < 16; ++i) e[i] = exp2f(p[i] - mrun);
    float s0 = (e[0] + e[1]) + (e[2] + e[3]);
    float s1 = (e[4] + e[5]) + (e[6] + e[7]);
    float s2 = (e[8] + e[9]) + (e[10] + e[11]);
    float s3 = (e[12] + e[13]) + (e[14] + e[15]);
    float ps = (s0 + s1) + (s2 + s3);
    ps += __shfl_xor(ps, 32);
    lsum += ps;

    // P B-frags in-register.
    // lane's S reg r holds kp = (r&3) + 8*(r>>2) + 4*hi.
    unsigned a0 = pk2(e[0], e[1]),   a1 = pk2(e[2], e[3]);
    unsigned b0 = pk2(e[4], e[5]),   b1 = pk2(e[6], e[7]);
    unsigned c0 = pk2(e[8], e[9]),   c1 = pk2(e[10], e[11]);
    unsigned d0 = pk2(e[12], e[13]), d1 = pk2(e[14], e[15]);
    lane32_swap(a0, b0, l);
    lane32_swap(a1, b1, l);
    lane32_swap(c0, d0, l);
    lane32_swap(c1, d1, l);
    uint4v u1; u1.x = a0; u1.y = a1; u1.z = b0; u1.w = b1;
    uint4v u2; u2.x = c0; u2.y = c1; u2.z = d0; u2.w = d1;
    short8 pf1 = __builtin_bit_cast(short8, u1);   // kp 0..15
    short8 pf2 = __builtin_bit_cast(short8, u2);   // kp 16..31

    // PV: O^T[d][q] accumulate; V A-frags from LDS
    //   V granule = kh*512 + (db*32+row)*2 + hi  (linear tiled layout,
    //   uniform 8 lanes per 16B slot -> conflict-free for b128)
    const char* sVc = (const char*)sV[cur];
    __builtin_amdgcn_s_setprio(1);
#pragma unroll
    for (int db = 0; db < 8; ++db) {
      short8 vf0 = *(const short8*)(sVc + ((db * 32 + row) * 2 + hi) * 16);
      short8 vf1 = *(const short8*)(sVc + 8192 + ((db * 32 + row) * 2 + hi) * 16);
      O[db] = __builtin_amdgcn_mfma_f32_32x32x16_bf16(vf0, pf1, O[db], 0, 0, 0);
      O[db] = __builtin_amdgcn_mfma_f32_32x32x16_bf16(vf1, pf2, O[db], 0, 0, 0);
    }
    __builtin_amdgcn_s_setprio(0);

    __syncthreads();   // drains stage loads + swaps buffers
  }

  float inv = 1.0f / lsum;
  unsigned short* aop = Oh + (size_t)kvhalf * (8192ull * 1024);
  size_t obase = ((size_t)(b * SEQ + q)) * DMODEL + h * HD;
#pragma unroll
  for (int db = 0; db < 8; ++db)
#pragma unroll
    for (int rg = 0; rg < 4; ++rg) {
      int dd = db * 32 + rg * 8 + hi * 4;
      uint2 pk;
      pk.x = pk2(O[db][rg * 4 + 0] * inv, O[db][rg * 4 + 1] * inv);
      pk.y = pk2(O[db][rg * 4 + 2] * inv, O[db][rg * 4 + 3] * inv);
      *(uint2*)&aop[obase + dd] = pk;
    }
  if (hi == 0)
    st[((size_t)kvhalf * 16 + bh) * 2048 + q] = make_float2(mrun, lsum);
}

// ---------------- combine KV-split halves ----------------
__global__ __launch_bounds__(256) void combine_kernel(
    const unsigned short* __restrict__ Oh,   // [2][8192][1024]
    const float2* __restrict__ st,           // [2][16][2048]
    unsigned short* __restrict__ ao) {       // [8192][1024]
  int rowg = blockIdx.x, t = threadIdx.x;
  int b = rowg >> 11, q = rowg & 2047;
  int col = t * 4;
  int bh = b * 4 + (col >> 8);
  float2 s0 = st[(size_t)bh * 2048 + q];
  float2 s1 = st[(16ull * 2048) + (size_t)bh * 2048 + q];
  float M = fmaxf(s0.x, s1.x);
  float w0 = s0.y * exp2f(s0.x - M);
  float w1 = s1.y * exp2f(s1.x - M);
  float inv = 1.0f / (w0 + w1);
  w0 *= inv; w1 *= inv;
  size_t base = (size_t)rowg * 1024 + col;
  uint2 ua = *(const uint2*)&Oh[base];
  uint2 ub = *(const uint2*)&Oh[8192ull * 1024 + base];
  unsigned short oa[4] = {(unsigned short)(ua.x & 0xFFFF), (unsigned short)(ua.x >> 16),
                          (unsigned short)(ua.y & 0xFFFF), (unsigned short)(ua.y >> 16)};
  unsigned short ob[4] = {(unsigned short)(ub.x & 0xFFFF), (unsigned short)(ub.x >> 16),
                          (unsigned short)(ub.y & 0xFFFF), (unsigned short)(ub.y >> 16)};
  float r[4];
#pragma unroll
  for (int j = 0; j < 4; ++j) r[j] = w0 * bf2f(oa[j]) + w1 * bf2f(ob[j]);
  uint2 pk;
  pk.x = pk2(r[0], r[1]);
  pk.y = pk2(r[2], r[3]);
  *(uint2*)&ao[base] = pk;
}

// ---------------- out projection + bias + residual -> y (fp32) ----------------
__global__ __launch_bounds__(256) void gemm_out_kernel(
    const unsigned short* __restrict__ A,    // attn_out [8192][1024]
    const unsigned short* __restrict__ Bt,   // woutT    [1024][1024]
    const float* __restrict__ bias,          // [1024]
    const float* __restrict__ x,             // [8192][1024] fp32
    float* __restrict__ y) {                 // [8192][1024] fp32
  __shared__ __align__(16) unsigned short sA[128 * 32];
  __shared__ __align__(16) unsigned short sB[128 * 32];
  const int t = threadIdx.x;
  const int l = t & 63, w = t >> 6;
  const int g = l >> 4, lr = l & 15;
  const int wr = w >> 1, wc = w & 1;
  const int row0 = blockIdx.y * 128;
  const int col0 = blockIdx.x * 128;

  f32x4 acc[4][4] = {};
  for (int kt = 0; kt < 1024; kt += 32) {
    __syncthreads();
#pragma unroll
    for (int i = 0; i < 2; ++i) {
      int e = i * 256 + t;
      async16(&sA[e * 8], A + (size_t)(row0 + (e >> 2)) * 1024 + kt + (e & 3) * 8);
      async16(&sB[e * 8], Bt + (size_t)(col0 + (e >> 2)) * 1024 + kt + (e & 3) * 8);
    }
    __syncthreads();
    short8 af[4], bf[4];
#pragma unroll
    for (int m = 0; m < 4; ++m)
      af[m] = *(const short8*)&sA[(wr * 64 + m * 16 + lr) * 32 + g * 8];
#pragma unroll
    for (int n = 0; n < 4; ++n)
      bf[n] = *(const short8*)&sB[(wc * 64 + n * 16 + lr) * 32 + g * 8];
#pragma unroll
    for (int m = 0; m < 4; ++m)
#pragma unroll
      for (int n = 0; n < 4; ++n)
        acc[m][n] = __builtin_amdgcn_mfma_f32_16x16x32_bf16(af[m], bf[n], acc[m][n], 0, 0, 0);
  }

#pragma unroll
  for (int m = 0; m < 4; ++m) {
    int rowb = row0 + wr * 64 + m * 16 + g * 4;
#pragma unroll
    for (int nn = 0; nn < 4; ++nn) {
      int col = col0 + wc * 64 + nn * 16 + lr;
      float bv = bias[col];
#pragma unroll
      for (int rr = 0; rr < 4; ++rr) {
        size_t idx = (size_t)(rowb + rr) * 1024 + col;
        y[idx] = acc[m][nn][rr] + bv + x[idx];
      }
    }
  }
}

// ---------------- LayerNorm over last dim (1024) ----------------
__global__ __launch_bounds__(256) void ln_kernel(
    const float* __restrict__ y, const float* __restrict__ gamma,
    const float* __restrict__ beta, float* __restrict__ out) {
  int row = blockIdx.x, t = threadIdx.x;
  float4 v = ((const float4*)(y + (size_t)row * 1024))[t];
  float s = v.x + v.y + v.z + v.w;
  float qs = v.x * v.x + v.y * v.y + v.z * v.z + v.w * v.w;
#pragma unroll
  for (int off = 1; off < 64; off <<= 1) {
    s += __shfl_xor(s, off);
    qs += __shfl_xor(qs, off);
  }
  __shared__ float ss[4], qq[4];
  if ((t & 63) == 0) { ss[t >> 6] = s; qq[t >> 6] = qs; }
  __syncthreads();
  s = ss[0] + ss[1] + ss[2] + ss[3];
  qs = qq[0] + qq[1] + qq[2] + qq[3];
  float mean = s * (1.0f / 1024.0f);
  float var = qs * (1.0f / 1024.0f) - mean * mean;
  float rstd = rsqrtf(var + 1e-5f);
  float4 gm = ((const float4*)gamma)[t];
  float4 bt = ((const float4*)beta)[t];
  float4 o;
  o.x = (v.x - mean) * rstd * gm.x + bt.x;
  o.y = (v.y - mean) * rstd * gm.y + bt.y;
  o.z = (v.z - mean) * rstd * gm.z + bt.z;
  o.w = (v.w - mean) * rstd * gm.w + bt.w;
  ((float4*)(out + (size_t)row * 1024))[t] = o;
}

// ---------------- launch ----------------
extern "C" void kernel_launch(void* const* d_in, const int* in_sizes, int n_in,
                              void* d_out, int out_size, void* d_ws, size_t ws_size,
                              hipStream_t stream) {
  const float* x      = (const float*)d_in[0];
  const float* w_qkv  = (const float*)d_in[1];
  const float* b_qkv  = (const float*)d_in[2];
  const float* w_out  = (const float*)d_in[3];
  const float* b_out  = (const float*)d_in[4];
  const float* gamma  = (const float*)d_in[5];
  const float* beta   = (const float*)d_in[6];
  float* out = (float*)d_out;

  char* ws = (char*)d_ws;
  unsigned short* xb    = (unsigned short*)(ws);                 // 16 MB
  unsigned short* wqkvT = (unsigned short*)(ws + (16u << 20));   //  6 MB
  unsigned short* woutT = (unsigned short*)(ws + (22u << 20));   //  2 MB
  unsigned short* qb    = (unsigned short*)(ws + (24u << 20));   // 16 MB
  unsigned short* kb    = (unsigned short*)(ws + (40u << 20));   // 16 MB
  unsigned short* vt    = (unsigned short*)(ws + (56u << 20));   // 16 MB
  unsigned short* ao    = (unsigned short*)(ws + (72u << 20));   // 16 MB
  unsigned short* Oh    = (unsigned short*)(ws + (88u << 20));   // 32 MB (dead after combine)
  float* y              = (float*)(ws + (88u << 20));            // 32 MB (after combine)
  float2* st            = (float2*)(ws + (16u << 20));           // 512 KB (overlays dead wqkvT)

  cast_bf16_kernel<<<(BATCH * SEQ * DMODEL) / (256 * 4), 256, 0, stream>>>(x, xb);
  transpose_cast_kernel<<<dim3(96, 32), dim3(32, 8), 0, stream>>>(w_qkv, wqkvT, 1024, 3072);
  transpose_cast_kernel<<<dim3(32, 32), dim3(32, 8), 0, stream>>>(w_out, woutT, 1024, 1024);
  gemm_qkv_kernel<<<dim3(24, 64), 256, 0, stream>>>(xb, wqkvT, b_qkv, qb, kb, vt);
  attn_kernel<<<512, 256, 0, stream>>>(qb, kb, vt, Oh, st);
  combine_kernel<<<BATCH * SEQ, 256, 0, stream>>>(Oh, st, ao);
  gemm_out_kernel<<<dim3(8, 64), 256, 0, stream>>>(ao, woutT, b_out, x, y);
  ln_kernel<<<BATCH * SEQ, 256, 0, stream>>>(y, gamma, beta, out);
}